// Round 6
// baseline (414.877 us; speedup 1.0000x reference)
//
#include <hip/hip_runtime.h>

typedef __attribute__((ext_vector_type(8))) short short8;
typedef __attribute__((ext_vector_type(4))) float float4f;

#define PADX 132
#define LOG_SLOPE -2.302585092994046f   // log(0.1)
#define LN2 0.6931471805599453f
#define NBLK 268

__device__ __forceinline__ float bf2f(unsigned int u) {
    return __builtin_bit_cast(float, u << 16);
}
__device__ __forceinline__ unsigned short f2bf(float f) {
    unsigned int x = __builtin_bit_cast(unsigned int, f);
    x += 0x7fff + ((x >> 16) & 1);   // round-to-nearest-even
    return (unsigned short)(x >> 16);
}

template<int ISF32>
__device__ __forceinline__ float ldv(const void* p, int i) {
    if (ISF32) return ((const float*)p)[i];
    return bf2f(((const unsigned short*)p)[i]);
}

// Per-wave dtype sniff: fp32 weights read as u16 pairs have uniform-random
// mantissa halves; bf16 weights have exponent fields in a narrow band.
__device__ __forceinline__ int detect_f32(const unsigned short* W1u, int lane) {
    unsigned int u = W1u[lane * 2];
    unsigned int e = (u >> 7) & 0xFF;
    int bad = (e < 64) || (e > 135);
    return __ballot(bad) != 0ull;
}

__device__ __forceinline__ float4f mfma16(short8 a, short8 b, float4f c) {
    return __builtin_amdgcn_mfma_f32_16x16x32_bf16(a, b, c, 0, 0, 0);
}

__device__ __forceinline__ void split8(float4f a, float4f b, short8& hi, short8& lo) {
#pragma unroll
    for (int j = 0; j < 4; ++j) {
        float v = a[j]; unsigned short h = f2bf(v);
        hi[j] = (short)h; lo[j] = (short)f2bf(v - bf2f(h));
        v = b[j]; h = f2bf(v);
        hi[4 + j] = (short)h; lo[4 + j] = (short)f2bf(v - bf2f(h));
    }
}

// out[16x128] = act( in[16x128] @ W^T + bias )
// MODE 0: out = leaky(v) | 1: out += v | 2: out = leaky(v) + count | 3: count only
template<int MODE, int ISF32>
__device__ __forceinline__ void matvec(const float* in, float* out,
                                       const void* __restrict__ W, int wofs,
                                       const void* __restrict__ bias, int bofs,
                                       int lane, int colb, int* cnt) {
    const int m = lane & 15, q = lane >> 4;
    const int c0 = colb + m, c1 = colb + 16 + m;
    float b0 = ldv<ISF32>(bias, bofs + c0);
    float b1v = ldv<ISF32>(bias, bofs + c1);
    float4f acc0 = {b0, b0, b0, b0};
    float4f acc1 = {b1v, b1v, b1v, b1v};
    __syncthreads();   // previous epilogue's writes to `in` now visible
#pragma unroll
    for (int kk = 0; kk < 4; ++kk) {
        const int kc = kk * 32 + q * 8;
        const float* xp = in + m * PADX + kc;
        short8 xh, xl;
        split8(*(const float4f*)xp, *(const float4f*)(xp + 4), xh, xl);
        if (ISF32) {
            const float* w0p = (const float*)W + wofs + c0 * 128 + kc;
            const float* w1p = (const float*)W + wofs + c1 * 128 + kc;
            short8 w0h, w0l, w1h, w1l;
            split8(*(const float4f*)w0p, *(const float4f*)(w0p + 4), w0h, w0l);
            split8(*(const float4f*)w1p, *(const float4f*)(w1p + 4), w1h, w1l);
            acc0 = mfma16(xh, w0h, acc0);
            acc0 = mfma16(xl, w0h, acc0);
            acc0 = mfma16(xh, w0l, acc0);
            acc1 = mfma16(xh, w1h, acc1);
            acc1 = mfma16(xl, w1h, acc1);
            acc1 = mfma16(xh, w1l, acc1);
        } else {
            short8 w0 = *(const short8*)((const unsigned short*)W + wofs + c0 * 128 + kc);
            short8 w1 = *(const short8*)((const unsigned short*)W + wofs + c1 * 128 + kc);
            acc0 = mfma16(xh, w0, acc0);
            acc0 = mfma16(xl, w0, acc0);
            acc1 = mfma16(xh, w1, acc1);
            acc1 = mfma16(xl, w1, acc1);
        }
    }
    __syncthreads();   // all reads of `in` done; in-place epilogue safe
    const int rbase = q * 4;
    int c[4];
#pragma unroll
    for (int r = 0; r < 4; ++r) {
        float v0 = acc0[r], v1 = acc1[r];
        int row = rbase + r;
        if (MODE == 1) {
            out[row * PADX + c0] += v0;
            out[row * PADX + c1] += v1;
        } else {
            if (MODE >= 2) c[r] = (v0 <= 0.0f) + (v1 <= 0.0f);
            if (MODE != 3) {
                out[row * PADX + c0] = v0 > 0.0f ? v0 : 0.1f * v0;
                out[row * PADX + c1] = v1 > 0.0f ? v1 : 0.1f * v1;
            }
        }
    }
    if (MODE >= 2) {
#pragma unroll
        for (int r = 0; r < 4; ++r) {
            int cc = c[r];
            cc += __shfl_xor(cc, 1);
            cc += __shfl_xor(cc, 2);
            cc += __shfl_xor(cc, 4);
            cc += __shfl_xor(cc, 8);
            if (m == 0) atomicAdd(&cnt[rbase + r], cc);
        }
    }
}

template<int ISF32>
__device__ __forceinline__ void fwd(int bid, int tid, int lane, float* lds,
        const void* x, const void* W1, const void* b1, const void* W2, const void* b2,
        const void* W3, const void* b3, void* out, float* ws) {
    const int r0 = bid * 16;
    float* X = lds;                      // [16][PADX]
    float* T = lds + 16 * PADX;          // [16][PADX]
    int* cnt = (int*)(lds + 32 * PADX);  // [16]
    for (int e = tid; e < 2048; e += 256) {
        int r = e >> 7, c = e & 127;
        X[r * PADX + c] = ldv<ISF32>(x, (r0 + r) * 128 + c);
    }
    if (tid < 16) cnt[tid] = 0;
    const int colb = (tid >> 6) * 32;
#pragma unroll 1
    for (int layer = 0; layer < 4; ++layer) {
        const int wofs = layer * 16384, bofs = layer * 128;
        matvec<0, ISF32>(X, T, W1, wofs, b1, bofs, lane, colb, cnt);  // T = leaky(h1)
        matvec<0, ISF32>(T, T, W2, wofs, b2, bofs, lane, colb, cnt);  // T = leaky(h2)
        matvec<1, ISF32>(T, X, W3, wofs, b3, bofs, lane, colb, cnt);  // X += f
        matvec<2, ISF32>(X, T, W1, wofs, b1, bofs, lane, colb, cnt);  // leaky(g1), count
        matvec<3, ISF32>(T, T, W2, wofs, b2, bofs, lane, colb, cnt);  // count g2
    }
    __syncthreads();
    for (int e = tid; e < 2048; e += 256) {
        int r = e >> 7, c = e & 127;
        float v = X[r * PADX + c];
        if (ISF32) ((float*)out)[(r0 + r) * 128 + c] = v;
        else ((unsigned short*)out)[(r0 + r) * 128 + c] = f2bf(v);
    }
    if (tid < 16) ws[64 + r0 + tid] = (float)cnt[tid];
}

// ---- register-resident unpivoted LU: matrix lives in VGPRs, only the
// pivot row/column round-trips through LDS (double-buffered, 1 barrier/step).
template<int ISF32>
__device__ __forceinline__ float lu_logdet(int id, int tid, float* lds,
        const void* W1, const void* W2, const void* W3) {
    const int wsel = id % 3;
    const void* Wm = (wsel == 0 ? W1 : (wsel == 1 ? W2 : W3));
    const int ofs = (id / 3) * 16384;
    const int tx = tid & 31, ty = tid >> 5;
    float* rowbuf = lds;        // [2][128]: pivot row k, cols 0..127
    float* colbuf = lds + 256;  // [2][128]: pivot col k, packed [ty*16+m]
    float4f V[16];              // A[ty+8m][4tx..4tx+3]
#pragma unroll
    for (int m = 0; m < 16; ++m) {
        int base = ofs + (ty + 8 * m) * 128 + 4 * tx;
        if (ISF32) {
            V[m] = *(const float4f*)((const float*)Wm + base);
        } else {
            ushort4 u = *(const ushort4*)((const unsigned short*)Wm + base);
            V[m] = (float4f){bf2f(u.x), bf2f(u.y), bf2f(u.z), bf2f(u.w)};
        }
    }
    // stage buffers for k = 0
    if (ty == 0) *(float4f*)&rowbuf[4 * tx] = V[0];
    if (tx == 0) {
#pragma unroll
        for (int m = 0; m < 16; ++m) colbuf[ty * 16 + m] = V[m][0];
    }
    __syncthreads();
    float logacc = 0.0f;
    for (int k = 0; k < 128; ++k) {
        const int buf = (k & 1) << 7;
        float akk = rowbuf[buf + k];                       // broadcast
        float4f rk = *(const float4f*)&rowbuf[buf + 4 * tx];
        float G[16];
        *(float4f*)&G[0]  = *(const float4f*)&colbuf[buf + ty * 16];
        *(float4f*)&G[4]  = *(const float4f*)&colbuf[buf + ty * 16 + 4];
        *(float4f*)&G[8]  = *(const float4f*)&colbuf[buf + ty * 16 + 8];
        *(float4f*)&G[12] = *(const float4f*)&colbuf[buf + ty * 16 + 12];
        float rp = 1.0f / akk;
        logacc += __log2f(fabsf(akk));   // redundant across threads; parallel
#pragma unroll
        for (int m = 0; m < 16; ++m) {
            int r = ty + 8 * m;
            float gg = (r > k) ? G[m] * rp : 0.0f;
            V[m][0] -= gg * rk[0]; V[m][1] -= gg * rk[1];
            V[m][2] -= gg * rk[2]; V[m][3] -= gg * rk[3];
        }
        if (k < 127) {
            const int nk = k + 1;
            const int nbuf = (nk & 1) << 7;
            if (ty == (nk & 7)) *(float4f*)&rowbuf[nbuf + 4 * tx] = V[nk >> 3];
            if (tx == (nk >> 2)) {
                // compile-time component extract (avoid dynamic vec index)
                switch (nk & 3) {
                case 0:
#pragma unroll
                    for (int m = 0; m < 16; ++m) colbuf[nbuf + ty * 16 + m] = V[m][0];
                    break;
                case 1:
#pragma unroll
                    for (int m = 0; m < 16; ++m) colbuf[nbuf + ty * 16 + m] = V[m][1];
                    break;
                case 2:
#pragma unroll
                    for (int m = 0; m < 16; ++m) colbuf[nbuf + ty * 16 + m] = V[m][2];
                    break;
                default:
#pragma unroll
                    for (int m = 0; m < 16; ++m) colbuf[nbuf + ty * 16 + m] = V[m][3];
                }
            }
        }
        __syncthreads();   // one barrier per step
    }
    return logacc * LN2;
}

__global__ __launch_bounds__(256) void k_main(
        const void* __restrict__ x,
        const void* __restrict__ W1, const void* __restrict__ b1,
        const void* __restrict__ W2, const void* __restrict__ b2,
        const void* __restrict__ W3, const void* __restrict__ b3,
        void* __restrict__ out, float* __restrict__ ws) {
    __shared__ float lds[16384];   // 64 KB
    __shared__ int s_last;
    const int tid = threadIdx.x;
    const int lane = tid & 63;
    const int isf32 = detect_f32((const unsigned short*)W1, lane);

    if (blockIdx.x < 12) {
        float ld = isf32 ? lu_logdet<1>(blockIdx.x, tid, lds, W1, W2, W3)
                         : lu_logdet<0>(blockIdx.x, tid, lds, W1, W2, W3);
        if (tid == 0) ws[2 + blockIdx.x] = ld;
    } else {
        const int bid = blockIdx.x - 12;
        if (isf32) fwd<1>(bid, tid, lane, lds, x, W1, b1, W2, b2, W3, b3, out, ws);
        else       fwd<0>(bid, tid, lane, lds, x, W1, b1, W2, b2, W3, b3, out, ws);
    }

    // ---- last-block finalize (replaces the k_fin launch) ----
    __threadfence();
    if (tid == 0) s_last = (atomicAdd((int*)ws, 1) == NBLK - 1);
    __syncthreads();
    if (!s_last) return;
    __threadfence();   // acquire: other blocks' ws/out writes now visible
    float s = 0.0f;
#pragma unroll
    for (int i = 0; i < 12; ++i) s += ws[2 + i];
    for (int b = tid; b < 4096; b += 256) {
        float v = s + LOG_SLOPE * ws[64 + b];
        if (isf32) ((float*)out)[524288 + b] = v;
        else ((unsigned short*)out)[524288 + b] = f2bf(v);
    }
}

extern "C" void kernel_launch(void* const* d_in, const int* in_sizes, int n_in,
                              void* d_out, int out_size, void* d_ws, size_t ws_size,
                              hipStream_t stream) {
    const void* x  = d_in[0];
    const void* W1 = d_in[1];
    const void* b1 = d_in[2];
    const void* W2 = d_in[3];
    const void* b2 = d_in[4];
    const void* W3 = d_in[5];
    const void* b3 = d_in[6];
    float* ws = (float*)d_ws;

    hipMemsetAsync(d_ws, 0, 8, stream);   // zero the finalize ticket
    hipLaunchKernelGGL(k_main, dim3(NBLK), dim3(256), 0, stream,
                       x, W1, b1, W2, b2, W3, b3, d_out, ws);
}

// Round 7
// 148.880 us; speedup vs baseline: 2.7867x; 2.7867x over previous
//
#include <hip/hip_runtime.h>

typedef __attribute__((ext_vector_type(8))) short short8;
typedef __attribute__((ext_vector_type(4))) float float4f;

#define PADX 132
#define LOG_SLOPE -2.302585092994046f   // log(0.1)
#define LN2 0.6931471805599453f
#define NBLK 268

__device__ __forceinline__ float bf2f(unsigned int u) {
    return __builtin_bit_cast(float, u << 16);
}
__device__ __forceinline__ unsigned short f2bf(float f) {
    unsigned int x = __builtin_bit_cast(unsigned int, f);
    x += 0x7fff + ((x >> 16) & 1);   // round-to-nearest-even
    return (unsigned short)(x >> 16);
}

template<int ISF32>
__device__ __forceinline__ float ldv(const void* p, int i) {
    if (ISF32) return ((const float*)p)[i];
    return bf2f(((const unsigned short*)p)[i]);
}

// Per-wave dtype sniff: fp32 weights read as u16 pairs have uniform-random
// mantissa halves; bf16 weights have exponent fields in a narrow band.
__device__ __forceinline__ int detect_f32(const unsigned short* W1u, int lane) {
    unsigned int u = W1u[lane * 2];
    unsigned int e = (u >> 7) & 0xFF;
    int bad = (e < 64) || (e > 135);
    return __ballot(bad) != 0ull;
}

__device__ __forceinline__ float4f mfma16(short8 a, short8 b, float4f c) {
    return __builtin_amdgcn_mfma_f32_16x16x32_bf16(a, b, c, 0, 0, 0);
}

__device__ __forceinline__ void split8(float4f a, float4f b, short8& hi, short8& lo) {
#pragma unroll
    for (int j = 0; j < 4; ++j) {
        float v = a[j]; unsigned short h = f2bf(v);
        hi[j] = (short)h; lo[j] = (short)f2bf(v - bf2f(h));
        v = b[j]; h = f2bf(v);
        hi[4 + j] = (short)h; lo[4 + j] = (short)f2bf(v - bf2f(h));
    }
}

// out[16x128] = act( in[16x128] @ W^T + bias )
// MODE 0: out = leaky(v) | 1: out += v | 2: out = leaky(v) + count | 3: count only
template<int MODE, int ISF32>
__device__ __forceinline__ void matvec(const float* in, float* out,
                                       const void* __restrict__ W, int wofs,
                                       const void* __restrict__ bias, int bofs,
                                       int lane, int colb, int* cnt) {
    const int m = lane & 15, q = lane >> 4;
    const int c0 = colb + m, c1 = colb + 16 + m;
    float b0 = ldv<ISF32>(bias, bofs + c0);
    float b1v = ldv<ISF32>(bias, bofs + c1);
    float4f acc0 = {b0, b0, b0, b0};
    float4f acc1 = {b1v, b1v, b1v, b1v};
    __syncthreads();   // previous epilogue's writes to `in` now visible
#pragma unroll
    for (int kk = 0; kk < 4; ++kk) {
        const int kc = kk * 32 + q * 8;
        const float* xp = in + m * PADX + kc;
        short8 xh, xl;
        split8(*(const float4f*)xp, *(const float4f*)(xp + 4), xh, xl);
        if (ISF32) {
            const float* w0p = (const float*)W + wofs + c0 * 128 + kc;
            const float* w1p = (const float*)W + wofs + c1 * 128 + kc;
            short8 w0h, w0l, w1h, w1l;
            split8(*(const float4f*)w0p, *(const float4f*)(w0p + 4), w0h, w0l);
            split8(*(const float4f*)w1p, *(const float4f*)(w1p + 4), w1h, w1l);
            acc0 = mfma16(xh, w0h, acc0);
            acc0 = mfma16(xl, w0h, acc0);
            acc0 = mfma16(xh, w0l, acc0);
            acc1 = mfma16(xh, w1h, acc1);
            acc1 = mfma16(xl, w1h, acc1);
            acc1 = mfma16(xh, w1l, acc1);
        } else {
            short8 w0 = *(const short8*)((const unsigned short*)W + wofs + c0 * 128 + kc);
            short8 w1 = *(const short8*)((const unsigned short*)W + wofs + c1 * 128 + kc);
            acc0 = mfma16(xh, w0, acc0);
            acc0 = mfma16(xl, w0, acc0);
            acc1 = mfma16(xh, w1, acc1);
            acc1 = mfma16(xl, w1, acc1);
        }
    }
    __syncthreads();   // all reads of `in` done; in-place epilogue safe
    const int rbase = q * 4;
    int c[4];
#pragma unroll
    for (int r = 0; r < 4; ++r) {
        float v0 = acc0[r], v1 = acc1[r];
        int row = rbase + r;
        if (MODE == 1) {
            out[row * PADX + c0] += v0;
            out[row * PADX + c1] += v1;
        } else {
            if (MODE >= 2) c[r] = (v0 <= 0.0f) + (v1 <= 0.0f);
            if (MODE != 3) {
                out[row * PADX + c0] = v0 > 0.0f ? v0 : 0.1f * v0;
                out[row * PADX + c1] = v1 > 0.0f ? v1 : 0.1f * v1;
            }
        }
    }
    if (MODE >= 2) {
#pragma unroll
        for (int r = 0; r < 4; ++r) {
            int cc = c[r];
            cc += __shfl_xor(cc, 1);
            cc += __shfl_xor(cc, 2);
            cc += __shfl_xor(cc, 4);
            cc += __shfl_xor(cc, 8);
            if (m == 0) atomicAdd(&cnt[rbase + r], cc);
        }
    }
}

template<int ISF32>
__device__ __forceinline__ void fwd(int bid, int tid, int lane, float* lds,
        const void* x, const void* W1, const void* b1, const void* W2, const void* b2,
        const void* W3, const void* b3, void* out, float* ws) {
    const int r0 = bid * 16;
    float* X = lds;                      // [16][PADX]
    float* T = lds + 16 * PADX;          // [16][PADX]
    int* cnt = (int*)(lds + 32 * PADX);  // [16]
    for (int e = tid; e < 2048; e += 256) {
        int r = e >> 7, c = e & 127;
        X[r * PADX + c] = ldv<ISF32>(x, (r0 + r) * 128 + c);
    }
    if (tid < 16) cnt[tid] = 0;
    const int colb = (tid >> 6) * 32;
#pragma unroll 1
    for (int layer = 0; layer < 4; ++layer) {
        const int wofs = layer * 16384, bofs = layer * 128;
        matvec<0, ISF32>(X, T, W1, wofs, b1, bofs, lane, colb, cnt);  // T = leaky(h1)
        matvec<0, ISF32>(T, T, W2, wofs, b2, bofs, lane, colb, cnt);  // T = leaky(h2)
        matvec<1, ISF32>(T, X, W3, wofs, b3, bofs, lane, colb, cnt);  // X += f
        matvec<2, ISF32>(X, T, W1, wofs, b1, bofs, lane, colb, cnt);  // leaky(g1), count
        matvec<3, ISF32>(T, T, W2, wofs, b2, bofs, lane, colb, cnt);  // count g2
    }
    __syncthreads();
    for (int e = tid; e < 2048; e += 256) {
        int r = e >> 7, c = e & 127;
        float v = X[r * PADX + c];
        if (ISF32) ((float*)out)[(r0 + r) * 128 + c] = v;
        else ((unsigned short*)out)[(r0 + r) * 128 + c] = f2bf(v);
    }
    if (tid < 16) ws[64 + r0 + tid] = (float)cnt[tid];
}

// ---- register-resident unpivoted LU: matrix lives in VGPRs, only the
// pivot row/column round-trips through LDS (double-buffered, 1 barrier/step).
// NOTE: no dynamic indexing of V[] anywhere — dynamic index demotes the
// whole array to scratch (round-6 regression: +3.6 MB WRITE_SIZE, 2.5x dur).
template<int ISF32>
__device__ __forceinline__ float lu_logdet(int id, int tid, float* lds,
        const void* W1, const void* W2, const void* W3) {
    const int wsel = id % 3;
    const void* Wm = (wsel == 0 ? W1 : (wsel == 1 ? W2 : W3));
    const int ofs = (id / 3) * 16384;
    const int tx = tid & 31, ty = tid >> 5;
    float* rowbuf = lds;        // [2][128]: pivot row k, cols 0..127
    float* colbuf = lds + 256;  // [2][128]: pivot col k, packed [ty*16+m]
    float4f V[16];              // A[ty+8m][4tx..4tx+3]
#pragma unroll
    for (int m = 0; m < 16; ++m) {
        int base = ofs + (ty + 8 * m) * 128 + 4 * tx;
        if (ISF32) {
            V[m] = *(const float4f*)((const float*)Wm + base);
        } else {
            ushort4 u = *(const ushort4*)((const unsigned short*)Wm + base);
            V[m] = (float4f){bf2f(u.x), bf2f(u.y), bf2f(u.z), bf2f(u.w)};
        }
    }
    // stage buffers for k = 0
    if (ty == 0) *(float4f*)&rowbuf[4 * tx] = V[0];
    if (tx == 0) {
#pragma unroll
        for (int m = 0; m < 16; ++m) colbuf[ty * 16 + m] = V[m][0];
    }
    __syncthreads();
    float logacc = 0.0f;
    for (int k = 0; k < 128; ++k) {
        const int buf = (k & 1) << 7;
        float akk = rowbuf[buf + k];                       // broadcast
        float4f rk = *(const float4f*)&rowbuf[buf + 4 * tx];
        float G[16];
        *(float4f*)&G[0]  = *(const float4f*)&colbuf[buf + ty * 16];
        *(float4f*)&G[4]  = *(const float4f*)&colbuf[buf + ty * 16 + 4];
        *(float4f*)&G[8]  = *(const float4f*)&colbuf[buf + ty * 16 + 8];
        *(float4f*)&G[12] = *(const float4f*)&colbuf[buf + ty * 16 + 12];
        float rp = 1.0f / akk;
        logacc += __log2f(fabsf(akk));   // redundant across threads; parallel
#pragma unroll
        for (int m = 0; m < 16; ++m) {
            int r = ty + 8 * m;
            float gg = (r > k) ? G[m] * rp : 0.0f;
            V[m][0] -= gg * rk[0]; V[m][1] -= gg * rk[1];
            V[m][2] -= gg * rk[2]; V[m][3] -= gg * rk[3];
        }
        if (k < 127) {
            const int nk = k + 1;
            const int nbuf = (nk & 1) << 7;
            // wave-uniform switch -> static V[m] stores (NO dynamic reg index)
            if (ty == (nk & 7)) {
                float4f* dst = (float4f*)&rowbuf[nbuf + 4 * tx];
                switch (nk >> 3) {
                case 0:  *dst = V[0];  break;
                case 1:  *dst = V[1];  break;
                case 2:  *dst = V[2];  break;
                case 3:  *dst = V[3];  break;
                case 4:  *dst = V[4];  break;
                case 5:  *dst = V[5];  break;
                case 6:  *dst = V[6];  break;
                case 7:  *dst = V[7];  break;
                case 8:  *dst = V[8];  break;
                case 9:  *dst = V[9];  break;
                case 10: *dst = V[10]; break;
                case 11: *dst = V[11]; break;
                case 12: *dst = V[12]; break;
                case 13: *dst = V[13]; break;
                case 14: *dst = V[14]; break;
                default: *dst = V[15]; break;
                }
            }
            if (tx == (nk >> 2)) {
                // compile-time component extract (avoid dynamic vec index)
                switch (nk & 3) {
                case 0:
#pragma unroll
                    for (int m = 0; m < 16; ++m) colbuf[nbuf + ty * 16 + m] = V[m][0];
                    break;
                case 1:
#pragma unroll
                    for (int m = 0; m < 16; ++m) colbuf[nbuf + ty * 16 + m] = V[m][1];
                    break;
                case 2:
#pragma unroll
                    for (int m = 0; m < 16; ++m) colbuf[nbuf + ty * 16 + m] = V[m][2];
                    break;
                default:
#pragma unroll
                    for (int m = 0; m < 16; ++m) colbuf[nbuf + ty * 16 + m] = V[m][3];
                }
            }
        }
        __syncthreads();   // one barrier per step
    }
    return logacc * LN2;
}

__global__ __launch_bounds__(256) void k_main(
        const void* __restrict__ x,
        const void* __restrict__ W1, const void* __restrict__ b1,
        const void* __restrict__ W2, const void* __restrict__ b2,
        const void* __restrict__ W3, const void* __restrict__ b3,
        void* __restrict__ out, float* __restrict__ ws) {
    __shared__ float lds[16384];   // 64 KB
    __shared__ int s_last;
    const int tid = threadIdx.x;
    const int lane = tid & 63;
    const int isf32 = detect_f32((const unsigned short*)W1, lane);

    if (blockIdx.x < 12) {
        float ld = isf32 ? lu_logdet<1>(blockIdx.x, tid, lds, W1, W2, W3)
                         : lu_logdet<0>(blockIdx.x, tid, lds, W1, W2, W3);
        if (tid == 0) ws[2 + blockIdx.x] = ld;
    } else {
        const int bid = blockIdx.x - 12;
        if (isf32) fwd<1>(bid, tid, lane, lds, x, W1, b1, W2, b2, W3, b3, out, ws);
        else       fwd<0>(bid, tid, lane, lds, x, W1, b1, W2, b2, W3, b3, out, ws);
    }

    // ---- last-block finalize (replaces a second kernel launch) ----
    __threadfence();
    if (tid == 0) s_last = (atomicAdd((int*)ws, 1) == NBLK - 1);
    __syncthreads();
    if (!s_last) return;
    __threadfence();   // acquire: other blocks' ws writes now visible
    float s = 0.0f;
#pragma unroll
    for (int i = 0; i < 12; ++i) s += ws[2 + i];
    for (int b = tid; b < 4096; b += 256) {
        float v = s + LOG_SLOPE * ws[64 + b];
        if (isf32) ((float*)out)[524288 + b] = v;
        else ((unsigned short*)out)[524288 + b] = f2bf(v);
    }
}

extern "C" void kernel_launch(void* const* d_in, const int* in_sizes, int n_in,
                              void* d_out, int out_size, void* d_ws, size_t ws_size,
                              hipStream_t stream) {
    const void* x  = d_in[0];
    const void* W1 = d_in[1];
    const void* b1 = d_in[2];
    const void* W2 = d_in[3];
    const void* b2 = d_in[4];
    const void* W3 = d_in[5];
    const void* b3 = d_in[6];
    float* ws = (float*)d_ws;

    hipMemsetAsync(d_ws, 0, 8, stream);   // zero the finalize ticket
    hipLaunchKernelGGL(k_main, dim3(NBLK), dim3(256), 0, stream,
                       x, W1, b1, W2, b2, W3, b3, d_out, ws);
}